// Round 2
// baseline (1844.988 us; speedup 1.0000x reference)
//
#include <hip/hip_runtime.h>
#include <hip/hip_bf16.h>

#define N_NODES 2048
#define D_NODE 128
#define QK_DIM 64
#define N_HEADS 8
#define E_DIM 8

typedef __hip_bfloat16 bf16;

__device__ __forceinline__ float bf2f(bf16 x) { return __bfloat162float(x); }

__device__ __forceinline__ void unpack2(unsigned u, float& a, float& b) {
  union { unsigned x; float f; } lo, hi;
  lo.x = u << 16; hi.x = u & 0xffff0000u;
  a = lo.f; b = hi.f;
}
__device__ __forceinline__ void unpack8(uint4 u, float* f) {
  unpack2(u.x, f[0], f[1]); unpack2(u.y, f[2], f[3]);
  unpack2(u.z, f[4], f[5]); unpack2(u.w, f[6], f[7]);
}

// ---- dtype-generic load/store helpers -------------------------------------
template <bool BF16>
__device__ __forceinline__ float ldv(const void* p, size_t i) {
  if constexpr (BF16) return bf2f(((const bf16*)p)[i]);
  else return ((const float*)p)[i];
}
template <bool BF16>
__device__ __forceinline__ void ld8v(const void* p, size_t i8, float* f) {
  if constexpr (BF16) {
    uint4 u = ((const uint4*)p)[i8];
    unpack8(u, f);
  } else {
    const float4* fp = (const float4*)p;
    float4 a = fp[2 * i8], b = fp[2 * i8 + 1];
    f[0] = a.x; f[1] = a.y; f[2] = a.z; f[3] = a.w;
    f[4] = b.x; f[5] = b.y; f[6] = b.z; f[7] = b.w;
  }
}
template <bool BF16>
__device__ __forceinline__ void stv(void* p, size_t i, float v) {
  if constexpr (BF16) ((bf16*)p)[i] = __float2bfloat16(v);
  else ((float*)p)[i] = v;
}
template <bool BF16>
__device__ __forceinline__ void st8v(void* p, size_t i8, const float* f) {
  if constexpr (BF16) {
    union { uint4 u; bf16 b[8]; } ou;
#pragma unroll
    for (int e = 0; e < 8; e++) ou.b[e] = __float2bfloat16(f[e]);
    ((uint4*)p)[i8] = ou.u;
  } else {
    float4 a = make_float4(f[0], f[1], f[2], f[3]);
    float4 b = make_float4(f[4], f[5], f[6], f[7]);
    ((float4*)p)[2 * i8] = a;
    ((float4*)p)[2 * i8 + 1] = b;
  }
}

// order-preserving float->uint encoding for atomicMax
__device__ __forceinline__ unsigned enc_f(float f) {
  unsigned u = __float_as_uint(f);
  return u ^ ((unsigned)(((int)u) >> 31) | 0x80000000u);
}
__device__ __forceinline__ float dec_f(unsigned u) {
  unsigned m = (((int)u) >> 31) ? 0x80000000u : 0xffffffffu;
  return __uint_as_float(u ^ m);
}

// K0: detect input dtype. adj[0]==1.0 always (self-loop). fp32 word0 ==
// 0x3F800000 (low16==0); bf16 word0 low16 == 0x3F80. Writes flag (1=bf16).
__global__ void k_detect(const unsigned* __restrict__ adj_words, int* __restrict__ flag) {
  if (threadIdx.x == 0 && blockIdx.x == 0) {
    int b = 0;
    for (int i = 0; i < 64; i++) {
      unsigned w = adj_words[i];
      if ((w & 0xFFFFu) == 0x3F80u) b = 1;
    }
    *flag = b;
  }
}

// K1: q/k/v projections. Output planes [h][n][64] fp32, q pre-scaled by 1/8.
template <bool BF16>
__global__ __launch_bounds__(256) void k_proj(
    const int* __restrict__ flag,
    const void* __restrict__ nodes, const void* __restrict__ WQ,
    const void* __restrict__ WK, const void* __restrict__ WV,
    float* __restrict__ q, float* __restrict__ k, float* __restrict__ v) {
  if ((*flag != 0) != BF16) return;
  int n = blockIdx.x, t = threadIdx.x;
  __shared__ float ns[D_NODE];
  if (t < D_NODE) ns[t] = ldv<BF16>(nodes, (size_t)n * D_NODE + t);
  __syncthreads();
  for (int c = t; c < QK_DIM * N_HEADS; c += 256) {
    float dq = 0.f, dk = 0.f, dv = 0.f;
    for (int ch = 0; ch < D_NODE / 8; ch++) {
      float fq[8], fk[8], fv[8];
      ld8v<BF16>(WQ, (size_t)c * (D_NODE / 8) + ch, fq);
      ld8v<BF16>(WK, (size_t)c * (D_NODE / 8) + ch, fk);
      ld8v<BF16>(WV, (size_t)c * (D_NODE / 8) + ch, fv);
#pragma unroll
      for (int j = 0; j < 8; j++) {
        float nsv = ns[ch * 8 + j];
        dq += fq[j] * nsv; dk += fk[j] * nsv; dv += fv[j] * nsv;
      }
    }
    int h = c & 7, d = c >> 3;
    size_t o = ((size_t)(h * N_NODES + n) << 6) + d;
    q[o] = dq * 0.125f;  // fold 1/sqrt(QK)
    k[o] = dk;
    v[o] = dv;
  }
}

// K2: modulated scores + edges_out + per-(n,h) row max.
template <bool BF16>
__global__ __launch_bounds__(256) void k_scores_edges(
    const int* __restrict__ flag,
    const void* __restrict__ adj, const void* __restrict__ edges,
    const void* __restrict__ We, const void* __restrict__ Weo,
    const float* __restrict__ q, const float* __restrict__ k,
    unsigned* __restrict__ rowmax, void* __restrict__ out_base) {
  if ((*flag != 0) != BF16) return;
  __shared__ float We_s[N_HEADS][E_DIM];
  __shared__ float Weo_s[E_DIM][N_HEADS];
  __shared__ unsigned lmax[16][N_HEADS];
  int t = threadIdx.x;
  if (t < 64) { We_s[t >> 3][t & 7] = ldv<BF16>(We, t); Weo_s[t >> 3][t & 7] = ldv<BF16>(Weo, t); }
  if (t < 128) lmax[t >> 3][t & 7] = 0u;
  __syncthreads();
  int r = t >> 4, c = t & 15;
  int n = blockIdx.y * 16 + r;
  int col = blockIdx.x * 16 + c;
  size_t pair = (size_t)n * N_NODES + col;
  float a = ldv<BF16>(adj, pair);
  float e8[8];
  ld8v<BF16>(edges, pair, e8);
  float smod[8];
#pragma unroll
  for (int h = 0; h < 8; h++) smod[h] = 0.f;
  if (a != 0.f) {
#pragma unroll 1
    for (int h = 0; h < 8; h++) {
      const float4* qp = (const float4*)(q + ((size_t)(h * N_NODES + n) << 6));
      const float4* kp = (const float4*)(k + ((size_t)(h * N_NODES + col) << 6));
      float dot = 0.f;
#pragma unroll
      for (int i = 0; i < 16; i++) {
        float4 qq = qp[i], kk = kp[i];
        dot += qq.x * kk.x + qq.y * kk.y + qq.z * kk.z + qq.w * kk.w;
      }
      float we = 0.f;
#pragma unroll
      for (int e = 0; e < 8; e++) we += e8[e] * We_s[h][e];
      smod[h] = dot * (we * a);
    }
  }
  // edges_out = l2norm(edges + smod @ Weo^T) over e
  float ss = 0.f;
  float eo[8];
#pragma unroll
  for (int e = 0; e < 8; e++) {
    float x = e8[e];
#pragma unroll
    for (int h = 0; h < 8; h++) x += smod[h] * Weo_s[e][h];
    eo[e] = x; ss += x * x;
  }
  float inv = 1.f / (sqrtf(ss) + 1e-8f);
#pragma unroll
  for (int e = 0; e < 8; e++) eo[e] *= inv;
  void* edges_out = (char*)out_base + (size_t)N_NODES * D_NODE * (BF16 ? 2 : 4);
  st8v<BF16>(edges_out, pair, eo);
  // row max (masked entries only)
  if (a != 0.f) {
#pragma unroll
    for (int h = 0; h < 8; h++) atomicMax(&lmax[r][h], enc_f(smod[h]));
  }
  __syncthreads();
  if (t < 128) {
    unsigned vmax = lmax[t >> 3][t & 7];
    if (vmax) atomicMax(&rowmax[(size_t)(blockIdx.y * 16 + (t >> 3)) * N_HEADS + (t & 7)], vmax);
  }
}

// K3: recompute smod, softmax (exp + rowsum), accumulate attn @ V -> hout [h][n][64] fp32.
template <bool BF16>
__global__ __launch_bounds__(256) void k_attn(
    const int* __restrict__ flag,
    const void* __restrict__ adj, const void* __restrict__ edges,
    const void* __restrict__ We,
    const float* __restrict__ q, const float* __restrict__ k,
    const float* __restrict__ v,
    const unsigned* __restrict__ rowmax, float* __restrict__ hout) {
  if ((*flag != 0) != BF16) return;
  int h = blockIdx.x, rt = blockIdx.y, t = threadIdx.x;
  __shared__ float We_s[E_DIM];
  __shared__ float p_s[16][17];
  if (t < E_DIM) We_s[t] = ldv<BF16>(We, h * E_DIM + t);
  __syncthreads();
  int r = t >> 4, c = t & 15;
  int n = rt * 16 + r;
  unsigned rm = rowmax[(size_t)n * N_HEADS + h];
  float mx = rm ? dec_f(rm) : 0.f;
  const float4* qp = (const float4*)(q + ((size_t)(h * N_NODES + n) << 6));
  float4 acc = make_float4(0.f, 0.f, 0.f, 0.f);
  float psum = 0.f;
  for (int ct = 0; ct < N_NODES / 16; ct++) {
    int col = ct * 16 + c;
    size_t pair = (size_t)n * N_NODES + col;
    float a = ldv<BF16>(adj, pair);
    float p = 0.f;
    if (a != 0.f) {
      float e8[8];
      ld8v<BF16>(edges, pair, e8);
      float we = 0.f;
#pragma unroll
      for (int e = 0; e < 8; e++) we += e8[e] * We_s[e];
      we *= a;
      const float4* kp = (const float4*)(k + ((size_t)(h * N_NODES + col) << 6));
      float dot = 0.f;
#pragma unroll
      for (int i = 0; i < 16; i++) {
        float4 qq = qp[i], kk = kp[i];
        dot += qq.x * kk.x + qq.y * kk.y + qq.z * kk.z + qq.w * kk.w;
      }
      p = __expf(dot * we - mx);
    }
    psum += p;
    p_s[r][c] = p;
    __syncthreads();
    const float4* vp = (const float4*)(v + ((size_t)(h * N_NODES + ct * 16) << 6));
#pragma unroll
    for (int cc = 0; cc < 16; cc++) {
      float pv = p_s[r][cc];
      float4 vv = vp[(size_t)cc * 16 + c];
      acc.x += pv * vv.x; acc.y += pv * vv.y; acc.z += pv * vv.z; acc.w += pv * vv.w;
    }
    __syncthreads();
  }
  p_s[r][c] = psum;
  __syncthreads();
  float tot = 0.f;
#pragma unroll
  for (int cc = 0; cc < 16; cc++) tot += p_s[r][cc];
  float inv = (tot > 0.f) ? 1.f / tot : 0.f;
  float4 res;
  res.x = acc.x * inv; res.y = acc.y * inv; res.z = acc.z * inv; res.w = acc.w * inv;
  ((float4*)hout)[(size_t)(h * N_NODES + n) * 16 + c] = res;
}

// K4: nodes_out = l2norm(nodes + h @ Wo^T + bo)
template <bool BF16>
__global__ __launch_bounds__(128) void k_out(
    const int* __restrict__ flag,
    const void* __restrict__ nodes, const void* __restrict__ Wo,
    const void* __restrict__ bo, const float* __restrict__ hout,
    void* __restrict__ out_base) {
  if ((*flag != 0) != BF16) return;
  int n = blockIdx.x, t = threadIdx.x;
  __shared__ float hv[QK_DIM * N_HEADS];
  __shared__ float red[128];
  for (int i = t; i < QK_DIM * N_HEADS; i += 128) {
    int d = i >> 3, hh = i & 7;
    hv[i] = hout[((size_t)(hh * N_NODES + n) << 6) + d];
  }
  __syncthreads();
  float val = ldv<BF16>(nodes, (size_t)n * D_NODE + t) + ldv<BF16>(bo, t);
  for (int ch = 0; ch < (QK_DIM * N_HEADS) / 8; ch++) {
    float wf[8];
    ld8v<BF16>(Wo, (size_t)t * ((QK_DIM * N_HEADS) / 8) + ch, wf);
#pragma unroll
    for (int j = 0; j < 8; j++) val += wf[j] * hv[ch * 8 + j];
  }
  red[t] = val * val;
  __syncthreads();
  for (int s = 64; s > 0; s >>= 1) {
    if (t < s) red[t] += red[t + s];
    __syncthreads();
  }
  float ss = red[0];
  stv<BF16>(out_base, (size_t)n * D_NODE + t, val / (sqrtf(ss) + 1e-8f));
}

extern "C" void kernel_launch(void* const* d_in, const int* in_sizes, int n_in,
                              void* d_out, int out_size, void* d_ws, size_t ws_size,
                              hipStream_t stream) {
  const void* nodes = d_in[0];
  const void* adj   = d_in[1];
  const void* edges = d_in[2];
  const void* WQ = d_in[3];
  const void* WK = d_in[4];
  const void* WV = d_in[5];
  const void* Wo = d_in[6];
  const void* bo = d_in[7];
  const void* We = d_in[8];
  const void* Weo = d_in[9];

  // ws layout: [flag int, pad to 256B][rowmax 64KB][q 4MB][k 4MB][v 4MB][hout 4MB]
  int* flag = (int*)d_ws;
  unsigned* rowmax = (unsigned*)((char*)d_ws + 256);
  float* qw = (float*)((char*)d_ws + 256 + (size_t)N_NODES * N_HEADS * 4);
  float* kw = qw + (size_t)N_NODES * QK_DIM * N_HEADS;
  float* vw = kw + (size_t)N_NODES * QK_DIM * N_HEADS;
  float* hout = vw + (size_t)N_NODES * QK_DIM * N_HEADS;

  hipMemsetAsync(rowmax, 0, (size_t)N_NODES * N_HEADS * sizeof(unsigned), stream);
  k_detect<<<1, 64, 0, stream>>>((const unsigned*)adj, flag);

  k_proj<false><<<N_NODES, 256, 0, stream>>>(flag, nodes, WQ, WK, WV, qw, kw, vw);
  k_proj<true ><<<N_NODES, 256, 0, stream>>>(flag, nodes, WQ, WK, WV, qw, kw, vw);

  dim3 g2(N_NODES / 16, N_NODES / 16);
  k_scores_edges<false><<<g2, 256, 0, stream>>>(flag, adj, edges, We, Weo, qw, kw, rowmax, d_out);
  k_scores_edges<true ><<<g2, 256, 0, stream>>>(flag, adj, edges, We, Weo, qw, kw, rowmax, d_out);

  dim3 g3(N_HEADS, N_NODES / 16);
  k_attn<false><<<g3, 256, 0, stream>>>(flag, adj, edges, We, qw, kw, vw, rowmax, hout);
  k_attn<true ><<<g3, 256, 0, stream>>>(flag, adj, edges, We, qw, kw, vw, rowmax, hout);

  k_out<false><<<N_NODES, 128, 0, stream>>>(flag, nodes, Wo, bo, hout, d_out);
  k_out<true ><<<N_NODES, 128, 0, stream>>>(flag, nodes, Wo, bo, hout, d_out);
}

// Round 3
// 944.530 us; speedup vs baseline: 1.9533x; 1.9533x over previous
//
#include <hip/hip_runtime.h>
#include <hip/hip_bf16.h>

#define N_NODES 2048
#define D_NODE 128
#define QK_DIM 64
#define N_HEADS 8
#define E_DIM 8

typedef __hip_bfloat16 bf16;
typedef unsigned short u16;
typedef __attribute__((ext_vector_type(8))) short bf16x8v;
typedef __attribute__((ext_vector_type(4))) float f32x4v;

__device__ __forceinline__ float bf2f(bf16 x) { return __bfloat162float(x); }
__device__ __forceinline__ float u2f(u16 u) { return __uint_as_float(((unsigned)u) << 16); }
__device__ __forceinline__ u16 f2bf(float f) {
  unsigned u = __float_as_uint(f);
  unsigned r = u + 0x7FFFu + ((u >> 16) & 1u);
  return (u16)(r >> 16);
}

__device__ __forceinline__ void unpack2(unsigned u, float& a, float& b) {
  union { unsigned x; float f; } lo, hi;
  lo.x = u << 16; hi.x = u & 0xffff0000u;
  a = lo.f; b = hi.f;
}
__device__ __forceinline__ void unpack8(uint4 u, float* f) {
  unpack2(u.x, f[0], f[1]); unpack2(u.y, f[2], f[3]);
  unpack2(u.z, f[4], f[5]); unpack2(u.w, f[6], f[7]);
}

template <bool BF16>
__device__ __forceinline__ float ldv(const void* p, size_t i) {
  if constexpr (BF16) return bf2f(((const bf16*)p)[i]);
  else return ((const float*)p)[i];
}
template <bool BF16>
__device__ __forceinline__ void ld8v(const void* p, size_t i8, float* f) {
  if constexpr (BF16) {
    uint4 u = ((const uint4*)p)[i8];
    unpack8(u, f);
  } else {
    const float4* fp = (const float4*)p;
    float4 a = fp[2 * i8], b = fp[2 * i8 + 1];
    f[0] = a.x; f[1] = a.y; f[2] = a.z; f[3] = a.w;
    f[4] = b.x; f[5] = b.y; f[6] = b.z; f[7] = b.w;
  }
}
template <bool BF16>
__device__ __forceinline__ void stv(void* p, size_t i, float v) {
  if constexpr (BF16) ((bf16*)p)[i] = __float2bfloat16(v);
  else ((float*)p)[i] = v;
}
template <bool BF16>
__device__ __forceinline__ void st8v(void* p, size_t i8, const float* f) {
  if constexpr (BF16) {
    union { uint4 u; u16 b[8]; } ou;
#pragma unroll
    for (int e = 0; e < 8; e++) ou.b[e] = f2bf(f[e]);
    ((uint4*)p)[i8] = ou.u;
  } else {
    ((float4*)p)[2 * i8] = make_float4(f[0], f[1], f[2], f[3]);
    ((float4*)p)[2 * i8 + 1] = make_float4(f[4], f[5], f[6], f[7]);
  }
}

// order-preserving float->uint encoding for atomicMax
__device__ __forceinline__ unsigned enc_f(float f) {
  unsigned u = __float_as_uint(f);
  return u ^ ((unsigned)(((int)u) >> 31) | 0x80000000u);
}
__device__ __forceinline__ float dec_f(unsigned u) {
  unsigned m = (((int)u) >> 31) ? 0x80000000u : 0xffffffffu;
  return __uint_as_float(u ^ m);
}

// K0: dtype detect via adj[0][0]==1.0 (self-loop). bf16 word0 low16==0x3F80.
__global__ void k_detect(const unsigned* __restrict__ adj_words, int* __restrict__ flag) {
  if (threadIdx.x == 0 && blockIdx.x == 0) {
    int b = 0;
    for (int i = 0; i < 64; i++)
      if ((adj_words[i] & 0xFFFFu) == 0x3F80u) b = 1;
    *flag = b;
  }
}

// K1: projections -> bf16 planes [h][n][64]: q (hi+lo, pre-scaled 1/8), k (hi+lo), v.
template <bool BF16>
__global__ __launch_bounds__(256) void k_proj(
    const int* __restrict__ flag,
    const void* __restrict__ nodes, const void* __restrict__ WQ,
    const void* __restrict__ WK, const void* __restrict__ WV,
    u16* __restrict__ qhi, u16* __restrict__ qlo,
    u16* __restrict__ khi, u16* __restrict__ klo, u16* __restrict__ vv) {
  if ((*flag != 0) != BF16) return;
  int n = blockIdx.x, t = threadIdx.x;
  __shared__ float ns[D_NODE];
  if (t < D_NODE) ns[t] = ldv<BF16>(nodes, (size_t)n * D_NODE + t);
  __syncthreads();
  int h = t >> 5, d0 = (t & 31) * 2;
  float dq[2], dk[2], dv[2];
#pragma unroll
  for (int j2 = 0; j2 < 2; j2++) {
    int c = (d0 + j2) * 8 + h;
    float aq = 0.f, ak = 0.f, av = 0.f;
    for (int ch = 0; ch < D_NODE / 8; ch++) {
      float fq[8], fk[8], fv[8];
      ld8v<BF16>(WQ, (size_t)c * (D_NODE / 8) + ch, fq);
      ld8v<BF16>(WK, (size_t)c * (D_NODE / 8) + ch, fk);
      ld8v<BF16>(WV, (size_t)c * (D_NODE / 8) + ch, fv);
#pragma unroll
      for (int j = 0; j < 8; j++) {
        float x = ns[ch * 8 + j];
        aq += fq[j] * x; ak += fk[j] * x; av += fv[j] * x;
      }
    }
    dq[j2] = aq * 0.125f; dk[j2] = ak; dv[j2] = av;
  }
  size_t base = ((size_t)(h * N_NODES + n) << 6) + d0;
  u16 qh0 = f2bf(dq[0]), qh1 = f2bf(dq[1]);
  u16 ql0 = f2bf(dq[0] - u2f(qh0)), ql1 = f2bf(dq[1] - u2f(qh1));
  u16 kh0 = f2bf(dk[0]), kh1 = f2bf(dk[1]);
  u16 kl0 = f2bf(dk[0] - u2f(kh0)), kl1 = f2bf(dk[1] - u2f(kh1));
  *(unsigned*)(qhi + base) = (unsigned)qh0 | ((unsigned)qh1 << 16);
  *(unsigned*)(qlo + base) = (unsigned)ql0 | ((unsigned)ql1 << 16);
  *(unsigned*)(khi + base) = (unsigned)kh0 | ((unsigned)kh1 << 16);
  *(unsigned*)(klo + base) = (unsigned)kl0 | ((unsigned)kl1 << 16);
  *(unsigned*)(vv  + base) = (unsigned)f2bf(dv[0]) | ((unsigned)f2bf(dv[1]) << 16);
}

// K1b: transpose v[h][n][64] -> vT[h][d][n] (dtype-independent, runs once).
__global__ __launch_bounds__(256) void k_vt(const u16* __restrict__ v, u16* __restrict__ vT) {
  int h = blockIdx.x, n0 = blockIdx.y * 64, t = threadIdx.x;
  __shared__ float vs[64][65];
  int nl = t >> 2, dd0 = (t & 3) * 16;
  const uint4* src = (const uint4*)(v + ((size_t)(h * N_NODES) + n0 + nl) * 64 + dd0);
  uint4 u0 = src[0], u1 = src[1];
  float f[16]; unpack8(u0, f); unpack8(u1, f + 8);
#pragma unroll
  for (int i = 0; i < 16; i++) vs[nl][dd0 + i] = f[i];
  __syncthreads();
  int dl = t >> 2, nf = (t & 3) * 16;
  union { uint4 q[2]; u16 s[16]; } ob;
#pragma unroll
  for (int i = 0; i < 16; i++) ob.s[i] = f2bf(vs[nf + i][dl]);
  uint4* dst = (uint4*)(vT + ((size_t)(h * 64 + dl)) * N_NODES + n0 + nf);
  dst[0] = ob.q[0]; dst[1] = ob.q[1];
}

// K2: per 16x16 pair tile: S = Q K^T via MFMA (hi/lo split), smod = S*we*adj,
// edges_out, per-(n,h) rowmax, smod -> global bf16 (-1e30 sentinel for masked).
template <bool BF16>
__global__ __launch_bounds__(256) void k_scores(
    const int* __restrict__ flag, int row_base, int rows_per,
    const void* __restrict__ adj, const void* __restrict__ edges,
    const void* __restrict__ We, const void* __restrict__ Weo,
    const u16* __restrict__ qhi, const u16* __restrict__ qlo,
    const u16* __restrict__ khi, const u16* __restrict__ klo,
    unsigned* __restrict__ rowmax, u16* __restrict__ smod_g,
    void* __restrict__ out_base) {
  if ((*flag != 0) != BF16) return;
  __shared__ float We_s[N_HEADS][E_DIM];
  __shared__ float Weo_s[E_DIM][N_HEADS];
  __shared__ float we_s[N_HEADS][256];
  __shared__ float smod_s[N_HEADS][256];
  __shared__ float a_s[256];
  __shared__ unsigned lmax[16][N_HEADS];
  int t = threadIdx.x;
  if (t < 64) { We_s[t >> 3][t & 7] = ldv<BF16>(We, t); Weo_s[t >> 3][t & 7] = ldv<BF16>(Weo, t); }
  if (t < 128) lmax[t >> 3][t & 7] = 0u;
  int row0 = row_base + blockIdx.y * 16, col0 = blockIdx.x * 16;
  int r = t >> 4, c = t & 15;
  int n = row0 + r, col = col0 + c;
  size_t pair = (size_t)n * N_NODES + col;
  float a = ldv<BF16>(adj, pair);
  float e8[8];
  ld8v<BF16>(edges, pair, e8);
  a_s[t] = a;
  __syncthreads();
#pragma unroll
  for (int h = 0; h < 8; h++) {
    float we = 0.f;
#pragma unroll
    for (int e = 0; e < 8; e++) we += e8[e] * We_s[h][e];
    we_s[h][t] = we * a;
  }
  __syncthreads();
  // MFMA: wave wv handles heads 2wv, 2wv+1
  {
    int wv = t >> 6, lane = t & 63, m0 = lane & 15, quad = lane >> 4;
#pragma unroll
    for (int hh = 0; hh < 2; hh++) {
      int h = wv * 2 + hh;
      f32x4v acc = {0.f, 0.f, 0.f, 0.f};
#pragma unroll
      for (int kh = 0; kh < 2; kh++) {
        size_t qoff = ((size_t)(h * N_NODES + row0 + m0) << 6) + kh * 32 + quad * 8;
        size_t koff = ((size_t)(h * N_NODES + col0 + m0) << 6) + kh * 32 + quad * 8;
        bf16x8v ah = *(const bf16x8v*)(qhi + qoff);
        bf16x8v al = *(const bf16x8v*)(qlo + qoff);
        bf16x8v bh = *(const bf16x8v*)(khi + koff);
        bf16x8v bl = *(const bf16x8v*)(klo + koff);
        acc = __builtin_amdgcn_mfma_f32_16x16x32_bf16(ah, bh, acc, 0, 0, 0);
        acc = __builtin_amdgcn_mfma_f32_16x16x32_bf16(ah, bl, acc, 0, 0, 0);
        acc = __builtin_amdgcn_mfma_f32_16x16x32_bf16(al, bh, acc, 0, 0, 0);
      }
#pragma unroll
      for (int reg = 0; reg < 4; reg++) {
        int pidx = (quad * 4 + reg) * 16 + m0;
        smod_s[h][pidx] = acc[reg] * we_s[h][pidx];
      }
    }
  }
  __syncthreads();
  // edges_out = l2norm(edges + smod @ Weo^T)
  {
    float ss = 0.f, eo[8];
#pragma unroll
    for (int e = 0; e < 8; e++) {
      float x = e8[e];
#pragma unroll
      for (int h = 0; h < 8; h++) x += smod_s[h][t] * Weo_s[e][h];
      eo[e] = x; ss += x * x;
    }
    float inv = 1.f / (sqrtf(ss) + 1e-8f);
#pragma unroll
    for (int e = 0; e < 8; e++) eo[e] *= inv;
    void* edges_out = (char*)out_base + (size_t)N_NODES * D_NODE * (BF16 ? 2 : 4);
    st8v<BF16>(edges_out, pair, eo);
  }
  // rowmax over masked entries
  if (a != 0.f) {
#pragma unroll
    for (int h = 0; h < 8; h++) atomicMax(&lmax[r][h], enc_f(smod_s[h][t]));
  }
  // smod -> global: thread group per head stores 8 consecutive pairs (16B)
  {
    int hg = t >> 5, p0 = (t & 31) * 8;
    union { uint4 q; u16 s[8]; } ob;
#pragma unroll
    for (int j = 0; j < 8; j++) {
      int p = p0 + j;
      float s = (a_s[p] != 0.f) ? smod_s[hg][p] : -1e30f;
      ob.s[j] = f2bf(s);
    }
    int lrow = blockIdx.y * 16 + (p0 >> 4);
    size_t gaddr = ((size_t)hg * rows_per + lrow) * N_NODES + col0 + (p0 & 15);
    *(uint4*)(smod_g + gaddr) = ob.q;
  }
  __syncthreads();
  if (t < 128) {
    unsigned vmax = lmax[t >> 3][t & 7];
    if (vmax) atomicMax(&rowmax[(size_t)(row0 + (t >> 3)) * N_HEADS + (t & 7)], vmax);
  }
}

// K3: softmax from smod + PV via MFMA. Block = (head, 16 rows); wave wv owns dims [16wv,16wv+16).
template <bool BF16>
__global__ __launch_bounds__(256) void k_attn(
    const int* __restrict__ flag, int row_base, int rows_per,
    const u16* __restrict__ smod_g, const u16* __restrict__ vT,
    const unsigned* __restrict__ rowmax, float* __restrict__ hout) {
  if ((*flag != 0) != BF16) return;
  int h = blockIdx.x, t = threadIdx.x;
  int n0l = blockIdx.y * 16;
  __shared__ u16 p_tile[16][32];
  __shared__ float psum_s[16][17];
  __shared__ float inv_s[16];
  int r = t >> 4, c2 = t & 15;
  unsigned rm = rowmax[(size_t)(row_base + n0l + r) * N_HEADS + h];
  float mx = rm ? dec_f(rm) : 0.f;
  int wv = t >> 6, lane = t & 63, m0 = lane & 15, quad = lane >> 4;
  f32x4v acc = {0.f, 0.f, 0.f, 0.f};
  float psum = 0.f;
  const u16* srow = smod_g + ((size_t)h * rows_per + n0l + r) * N_NODES;
  for (int ct = 0; ct < N_NODES / 32; ct++) {
    unsigned w = *(const unsigned*)(srow + ct * 32 + 2 * c2);
    float s0, s1; unpack2(w, s0, s1);
    float p0 = __expf(s0 - mx), p1 = __expf(s1 - mx);
    psum += p0 + p1;
    *(unsigned*)(&p_tile[r][c2 * 2]) = (unsigned)f2bf(p0) | ((unsigned)f2bf(p1) << 16);
    __syncthreads();
    bf16x8v ap = *(const bf16x8v*)((const char*)p_tile + m0 * 64 + quad * 16);
    bf16x8v bp = *(const bf16x8v*)(vT + ((size_t)(h * 64 + wv * 16 + m0)) * N_NODES + ct * 32 + quad * 8);
    acc = __builtin_amdgcn_mfma_f32_16x16x32_bf16(ap, bp, acc, 0, 0, 0);
    __syncthreads();
  }
  psum_s[r][c2] = psum;
  __syncthreads();
  if (t < 16) {
    float tot = 0.f;
#pragma unroll
    for (int i = 0; i < 16; i++) tot += psum_s[t][i];
    inv_s[t] = (tot > 0.f) ? 1.f / tot : 0.f;
  }
  __syncthreads();
#pragma unroll
  for (int reg = 0; reg < 4; reg++) {
    int row = quad * 4 + reg;
    float out = acc[reg] * inv_s[row];
    hout[((size_t)(h * N_NODES + row_base + n0l + row) << 6) + wv * 16 + m0] = out;
  }
}

// K4: nodes_out = l2norm(nodes + h @ Wo^T + bo)
template <bool BF16>
__global__ __launch_bounds__(128) void k_out(
    const int* __restrict__ flag,
    const void* __restrict__ nodes, const void* __restrict__ Wo,
    const void* __restrict__ bo, const float* __restrict__ hout,
    void* __restrict__ out_base) {
  if ((*flag != 0) != BF16) return;
  int n = blockIdx.x, t = threadIdx.x;
  __shared__ float hv[QK_DIM * N_HEADS];
  __shared__ float red[128];
  for (int i = t; i < QK_DIM * N_HEADS; i += 128) {
    int d = i >> 3, hh = i & 7;
    hv[i] = hout[((size_t)(hh * N_NODES + n) << 6) + d];
  }
  __syncthreads();
  float val = ldv<BF16>(nodes, (size_t)n * D_NODE + t) + ldv<BF16>(bo, t);
  for (int ch = 0; ch < (QK_DIM * N_HEADS) / 8; ch++) {
    float wf[8];
    ld8v<BF16>(Wo, (size_t)t * ((QK_DIM * N_HEADS) / 8) + ch, wf);
#pragma unroll
    for (int j = 0; j < 8; j++) val += wf[j] * hv[ch * 8 + j];
  }
  red[t] = val * val;
  __syncthreads();
  for (int s = 64; s > 0; s >>= 1) {
    if (t < s) red[t] += red[t + s];
    __syncthreads();
  }
  float ss = red[0];
  stv<BF16>(out_base, (size_t)n * D_NODE + t, val / (sqrtf(ss) + 1e-8f));
}

extern "C" void kernel_launch(void* const* d_in, const int* in_sizes, int n_in,
                              void* d_out, int out_size, void* d_ws, size_t ws_size,
                              hipStream_t stream) {
  const void* nodes = d_in[0];
  const void* adj   = d_in[1];
  const void* edges = d_in[2];
  const void* WQ = d_in[3];
  const void* WK = d_in[4];
  const void* WV = d_in[5];
  const void* Wo = d_in[6];
  const void* bo = d_in[7];
  const void* We = d_in[8];
  const void* Weo = d_in[9];

  // ws layout (bytes):
  // [0,256): flag | [256, 256+64K): rowmax | 6 bf16 planes of 2MB each:
  // qhi qlo khi klo v vT | hout fp32 4MB | smod bf16 (67MB / nslices)
  char* w = (char*)d_ws;
  int* flag = (int*)w;
  unsigned* rowmax = (unsigned*)(w + 256);
  size_t off = 256 + (size_t)N_NODES * N_HEADS * 4;
  const size_t PLANE = (size_t)N_HEADS * N_NODES * QK_DIM * 2;  // 2 MB
  u16* qhi = (u16*)(w + off);            off += PLANE;
  u16* qlo = (u16*)(w + off);            off += PLANE;
  u16* khi = (u16*)(w + off);            off += PLANE;
  u16* klo = (u16*)(w + off);            off += PLANE;
  u16* vv  = (u16*)(w + off);            off += PLANE;
  u16* vT  = (u16*)(w + off);            off += PLANE;
  float* hout = (float*)(w + off);       off += (size_t)N_NODES * QK_DIM * N_HEADS * 4;
  u16* smod_g = (u16*)(w + off);
  const size_t SMOD_FULL = (size_t)N_HEADS * N_NODES * N_NODES * 2;  // 67 MB

  int nsl = 128;
  for (int s = 1; s <= 128; s *= 2) {
    if (off + SMOD_FULL / s <= ws_size) { nsl = s; break; }
  }
  int rows_per = N_NODES / nsl;

  hipMemsetAsync(rowmax, 0, (size_t)N_NODES * N_HEADS * sizeof(unsigned), stream);
  k_detect<<<1, 64, 0, stream>>>((const unsigned*)adj, flag);

  k_proj<false><<<N_NODES, 256, 0, stream>>>(flag, nodes, WQ, WK, WV, qhi, qlo, khi, klo, vv);
  k_proj<true ><<<N_NODES, 256, 0, stream>>>(flag, nodes, WQ, WK, WV, qhi, qlo, khi, klo, vv);
  k_vt<<<dim3(N_HEADS, N_NODES / 64), 256, 0, stream>>>(vv, vT);

  for (int s = 0; s < nsl; s++) {
    int row_base = s * rows_per;
    dim3 g2(N_NODES / 16, rows_per / 16);
    k_scores<false><<<g2, 256, 0, stream>>>(flag, row_base, rows_per, adj, edges, We, Weo,
                                            qhi, qlo, khi, klo, rowmax, smod_g, d_out);
    k_scores<true ><<<g2, 256, 0, stream>>>(flag, row_base, rows_per, adj, edges, We, Weo,
                                            qhi, qlo, khi, klo, rowmax, smod_g, d_out);
    dim3 g3(N_HEADS, rows_per / 16);
    k_attn<false><<<g3, 256, 0, stream>>>(flag, row_base, rows_per, smod_g, vT, rowmax, hout);
    k_attn<true ><<<g3, 256, 0, stream>>>(flag, row_base, rows_per, smod_g, vT, rowmax, hout);
  }

  k_out<false><<<N_NODES, 128, 0, stream>>>(flag, nodes, Wo, bo, hout, d_out);
  k_out<true ><<<N_NODES, 128, 0, stream>>>(flag, nodes, Wo, bo, hout, d_out);
}

// Round 4
// 545.181 us; speedup vs baseline: 3.3842x; 1.7325x over previous
//
#include <hip/hip_runtime.h>
#include <hip/hip_bf16.h>

#define N_NODES 2048
#define D_NODE 128
#define QK_DIM 64
#define N_HEADS 8
#define E_DIM 8

typedef __hip_bfloat16 bf16;
typedef unsigned short u16;
typedef __attribute__((ext_vector_type(8))) short bf16x8v;
typedef __attribute__((ext_vector_type(4))) float f32x4v;

__device__ __forceinline__ float bf2f(bf16 x) { return __bfloat162float(x); }
__device__ __forceinline__ float u2f(u16 u) { return __uint_as_float(((unsigned)u) << 16); }
__device__ __forceinline__ u16 f2bf(float f) {
  unsigned u = __float_as_uint(f);
  unsigned r = u + 0x7FFFu + ((u >> 16) & 1u);
  return (u16)(r >> 16);
}

__device__ __forceinline__ void unpack2(unsigned u, float& a, float& b) {
  union { unsigned x; float f; } lo, hi;
  lo.x = u << 16; hi.x = u & 0xffff0000u;
  a = lo.f; b = hi.f;
}
__device__ __forceinline__ void unpack8(uint4 u, float* f) {
  unpack2(u.x, f[0], f[1]); unpack2(u.y, f[2], f[3]);
  unpack2(u.z, f[4], f[5]); unpack2(u.w, f[6], f[7]);
}

template <bool BF16>
__device__ __forceinline__ float ldv(const void* p, size_t i) {
  if constexpr (BF16) return bf2f(((const bf16*)p)[i]);
  else return ((const float*)p)[i];
}
template <bool BF16>
__device__ __forceinline__ void ld8v(const void* p, size_t i8, float* f) {
  if constexpr (BF16) {
    uint4 u = ((const uint4*)p)[i8];
    unpack8(u, f);
  } else {
    const float4* fp = (const float4*)p;
    float4 a = fp[2 * i8], b = fp[2 * i8 + 1];
    f[0] = a.x; f[1] = a.y; f[2] = a.z; f[3] = a.w;
    f[4] = b.x; f[5] = b.y; f[6] = b.z; f[7] = b.w;
  }
}
template <bool BF16>
__device__ __forceinline__ void stv(void* p, size_t i, float v) {
  if constexpr (BF16) ((bf16*)p)[i] = __float2bfloat16(v);
  else ((float*)p)[i] = v;
}
template <bool BF16>
__device__ __forceinline__ void st8v(void* p, size_t i8, const float* f) {
  if constexpr (BF16) {
    union { uint4 u; u16 b[8]; } ou;
#pragma unroll
    for (int e = 0; e < 8; e++) ou.b[e] = f2bf(f[e]);
    ((uint4*)p)[i8] = ou.u;
  } else {
    ((float4*)p)[2 * i8] = make_float4(f[0], f[1], f[2], f[3]);
    ((float4*)p)[2 * i8 + 1] = make_float4(f[4], f[5], f[6], f[7]);
  }
}

// MFMA fragment load: 8 consecutive bf16 elements starting at elem (16B-aligned).
template <bool BF16>
__device__ __forceinline__ bf16x8v ld_frag(const void* p, size_t elem) {
  if constexpr (BF16) {
    return *(const bf16x8v*)((const u16*)p + elem);
  } else {
    const float4* fp = (const float4*)p;
    float4 a = fp[elem / 4], b = fp[elem / 4 + 1];
    union { bf16x8v v; u16 s[8]; } o;
    o.s[0] = f2bf(a.x); o.s[1] = f2bf(a.y); o.s[2] = f2bf(a.z); o.s[3] = f2bf(a.w);
    o.s[4] = f2bf(b.x); o.s[5] = f2bf(b.y); o.s[6] = f2bf(b.z); o.s[7] = f2bf(b.w);
    return o.v;
  }
}

// order-preserving float->uint encoding for atomicMax
__device__ __forceinline__ unsigned enc_f(float f) {
  unsigned u = __float_as_uint(f);
  return u ^ ((unsigned)(((int)u) >> 31) | 0x80000000u);
}
__device__ __forceinline__ float dec_f(unsigned u) {
  unsigned m = (((int)u) >> 31) ? 0x80000000u : 0xffffffffu;
  return __uint_as_float(u ^ m);
}

// K0: dtype detect via adj[0][0]==1.0 (self-loop). bf16 word0 low16==0x3F80.
__global__ void k_detect(const unsigned* __restrict__ adj_words, int* __restrict__ flag) {
  if (threadIdx.x == 0 && blockIdx.x == 0) {
    int b = 0;
    for (int i = 0; i < 64; i++)
      if ((adj_words[i] & 0xFFFFu) == 0x3F80u) b = 1;
    *flag = b;
  }
}

// K1: projections as MFMA GEMM. Block = 16 nodes x 64 features (4 waves x 16 feat).
// grid (N/16, 24): blockIdx.y -> matrix = y>>3 (0=Q,1=K,2=V), c0 = (y&7)*64.
// Q/K results stored hi/lo split to planes [h][n][64]; V stored directly as vT[h][d][n].
template <bool BF16>
__global__ __launch_bounds__(256) void k_proj(
    const int* __restrict__ flag,
    const void* __restrict__ nodes, const void* __restrict__ WQ,
    const void* __restrict__ WK, const void* __restrict__ WV,
    u16* __restrict__ qhi, u16* __restrict__ qlo,
    u16* __restrict__ khi, u16* __restrict__ klo, u16* __restrict__ vT) {
  if ((*flag != 0) != BF16) return;
  int t = threadIdx.x;
  int n0 = blockIdx.x * 16;
  int g = blockIdx.y;
  int mat = g >> 3;
  const void* W = (mat == 0) ? WQ : (mat == 1) ? WK : WV;
  int wv = t >> 6, lane = t & 63, m0 = lane & 15, quad = lane >> 4;
  int c = (g & 7) * 64 + wv * 16 + m0;  // feature row of W (within matrix)
  f32x4v acc = {0.f, 0.f, 0.f, 0.f};
#pragma unroll
  for (int kk = 0; kk < 4; kk++) {
    bf16x8v af = ld_frag<BF16>(nodes, (size_t)(n0 + m0) * D_NODE + kk * 32 + quad * 8);
    bf16x8v bfr = ld_frag<BF16>(W, (size_t)c * D_NODE + kk * 32 + quad * 8);
    acc = __builtin_amdgcn_mfma_f32_16x16x32_bf16(af, bfr, acc, 0, 0, 0);
  }
  // C/D: col(feature) = lane&15 -> c above; row(node) = quad*4 + reg.
  int d = c >> 3, h = c & 7;
  if (mat == 2) {
    union { unsigned w[2]; u16 s[4]; } ob;
#pragma unroll
    for (int reg = 0; reg < 4; reg++) ob.s[reg] = f2bf(acc[reg]);
    int n = n0 + quad * 4;
    unsigned* dst = (unsigned*)(vT + ((size_t)(h * QK_DIM + d)) * N_NODES + n);
    dst[0] = ob.w[0]; dst[1] = ob.w[1];
  } else {
    u16* hiP = (mat == 0) ? qhi : khi;
    u16* loP = (mat == 0) ? qlo : klo;
    float scale = (mat == 0) ? 0.125f : 1.f;  // fold 1/sqrt(QK) into q
#pragma unroll
    for (int reg = 0; reg < 4; reg++) {
      int n = n0 + quad * 4 + reg;
      float vq = acc[reg] * scale;
      u16 hi = f2bf(vq);
      u16 lo = f2bf(vq - u2f(hi));
      size_t o = ((size_t)(h * N_NODES + n) << 6) + d;
      hiP[o] = hi; loP[o] = lo;
    }
  }
}

// K2: per 16x16 pair tile: S = Q K^T via MFMA (hi/lo split), smod = S*we*adj,
// edges_out, per-(n,h) rowmax, smod -> global bf16 (-1e30 sentinel for masked).
template <bool BF16>
__global__ __launch_bounds__(256) void k_scores(
    const int* __restrict__ flag, int row_base, int rows_per,
    const void* __restrict__ adj, const void* __restrict__ edges,
    const void* __restrict__ We, const void* __restrict__ Weo,
    const u16* __restrict__ qhi, const u16* __restrict__ qlo,
    const u16* __restrict__ khi, const u16* __restrict__ klo,
    unsigned* __restrict__ rowmax, u16* __restrict__ smod_g,
    void* __restrict__ out_base) {
  if ((*flag != 0) != BF16) return;
  __shared__ float We_s[N_HEADS][E_DIM];
  __shared__ float Weo_s[E_DIM][N_HEADS];
  __shared__ float we_s[N_HEADS][256];
  __shared__ float smod_s[N_HEADS][256];
  __shared__ float a_s[256];
  __shared__ unsigned lmax[16][N_HEADS];
  int t = threadIdx.x;
  if (t < 64) { We_s[t >> 3][t & 7] = ldv<BF16>(We, t); Weo_s[t >> 3][t & 7] = ldv<BF16>(Weo, t); }
  if (t < 128) lmax[t >> 3][t & 7] = 0u;
  int row0 = row_base + blockIdx.y * 16, col0 = blockIdx.x * 16;
  int r = t >> 4, c = t & 15;
  int n = row0 + r, col = col0 + c;
  size_t pair = (size_t)n * N_NODES + col;
  float a = ldv<BF16>(adj, pair);
  float e8[8];
  ld8v<BF16>(edges, pair, e8);
  a_s[t] = a;
  __syncthreads();
#pragma unroll
  for (int h = 0; h < 8; h++) {
    float we = 0.f;
#pragma unroll
    for (int e = 0; e < 8; e++) we += e8[e] * We_s[h][e];
    we_s[h][t] = we * a;
  }
  __syncthreads();
  // MFMA: wave wv handles heads 2wv, 2wv+1
  {
    int wv = t >> 6, lane = t & 63, m0 = lane & 15, quad = lane >> 4;
#pragma unroll
    for (int hh = 0; hh < 2; hh++) {
      int h = wv * 2 + hh;
      f32x4v acc = {0.f, 0.f, 0.f, 0.f};
#pragma unroll
      for (int kh = 0; kh < 2; kh++) {
        size_t qoff = ((size_t)(h * N_NODES + row0 + m0) << 6) + kh * 32 + quad * 8;
        size_t koff = ((size_t)(h * N_NODES + col0 + m0) << 6) + kh * 32 + quad * 8;
        bf16x8v ah = *(const bf16x8v*)(qhi + qoff);
        bf16x8v al = *(const bf16x8v*)(qlo + qoff);
        bf16x8v bh = *(const bf16x8v*)(khi + koff);
        bf16x8v bl = *(const bf16x8v*)(klo + koff);
        acc = __builtin_amdgcn_mfma_f32_16x16x32_bf16(ah, bh, acc, 0, 0, 0);
        acc = __builtin_amdgcn_mfma_f32_16x16x32_bf16(ah, bl, acc, 0, 0, 0);
        acc = __builtin_amdgcn_mfma_f32_16x16x32_bf16(al, bh, acc, 0, 0, 0);
      }
#pragma unroll
      for (int reg = 0; reg < 4; reg++) {
        int pidx = (quad * 4 + reg) * 16 + m0;
        smod_s[h][pidx] = acc[reg] * we_s[h][pidx];
      }
    }
  }
  __syncthreads();
  // edges_out = l2norm(edges + smod @ Weo^T)
  {
    float ss = 0.f, eo[8];
#pragma unroll
    for (int e = 0; e < 8; e++) {
      float x = e8[e];
#pragma unroll
      for (int h = 0; h < 8; h++) x += smod_s[h][t] * Weo_s[e][h];
      eo[e] = x; ss += x * x;
    }
    float inv = 1.f / (sqrtf(ss) + 1e-8f);
#pragma unroll
    for (int e = 0; e < 8; e++) eo[e] *= inv;
    void* edges_out = (char*)out_base + (size_t)N_NODES * D_NODE * (BF16 ? 2 : 4);
    st8v<BF16>(edges_out, pair, eo);
  }
  if (a != 0.f) {
#pragma unroll
    for (int h = 0; h < 8; h++) atomicMax(&lmax[r][h], enc_f(smod_s[h][t]));
  }
  // smod -> global: thread group per head stores 8 consecutive pairs (16B)
  {
    int hg = t >> 5, p0 = (t & 31) * 8;
    union { uint4 q; u16 s[8]; } ob;
#pragma unroll
    for (int j = 0; j < 8; j++) {
      int p = p0 + j;
      float s = (a_s[p] != 0.f) ? smod_s[hg][p] : -1e30f;
      ob.s[j] = f2bf(s);
    }
    int lrow = blockIdx.y * 16 + (p0 >> 4);
    size_t gaddr = ((size_t)hg * rows_per + lrow) * N_NODES + col0 + (p0 & 15);
    *(uint4*)(smod_g + gaddr) = ob.q;
  }
  __syncthreads();
  if (t < 128) {
    unsigned vmax = lmax[t >> 3][t & 7];
    if (vmax) atomicMax(&rowmax[(size_t)(row0 + (t >> 3)) * N_HEADS + (t & 7)], vmax);
  }
}

// K3: softmax from smod + PV via MFMA. Block = (head, 16 rows); wave wv owns dims [16wv,16wv+16).
template <bool BF16>
__global__ __launch_bounds__(256) void k_attn(
    const int* __restrict__ flag, int row_base, int rows_per,
    const u16* __restrict__ smod_g, const u16* __restrict__ vT,
    const unsigned* __restrict__ rowmax, float* __restrict__ hout) {
  if ((*flag != 0) != BF16) return;
  int h = blockIdx.x, t = threadIdx.x;
  int n0l = blockIdx.y * 16;
  __shared__ u16 p_tile[16][32];
  __shared__ float psum_s[16][17];
  __shared__ float inv_s[16];
  int r = t >> 4, c2 = t & 15;
  unsigned rm = rowmax[(size_t)(row_base + n0l + r) * N_HEADS + h];
  float mx = rm ? dec_f(rm) : 0.f;
  int wv = t >> 6, lane = t & 63, m0 = lane & 15, quad = lane >> 4;
  f32x4v acc = {0.f, 0.f, 0.f, 0.f};
  float psum = 0.f;
  const u16* srow = smod_g + ((size_t)h * rows_per + n0l + r) * N_NODES;
  for (int ct = 0; ct < N_NODES / 32; ct++) {
    unsigned w = *(const unsigned*)(srow + ct * 32 + 2 * c2);
    float s0, s1; unpack2(w, s0, s1);
    float p0 = __expf(s0 - mx), p1 = __expf(s1 - mx);
    psum += p0 + p1;
    *(unsigned*)(&p_tile[r][c2 * 2]) = (unsigned)f2bf(p0) | ((unsigned)f2bf(p1) << 16);
    __syncthreads();
    bf16x8v ap = *(const bf16x8v*)((const char*)p_tile + m0 * 64 + quad * 16);
    bf16x8v bp = *(const bf16x8v*)(vT + ((size_t)(h * 64 + wv * 16 + m0)) * N_NODES + ct * 32 + quad * 8);
    acc = __builtin_amdgcn_mfma_f32_16x16x32_bf16(ap, bp, acc, 0, 0, 0);
    __syncthreads();
  }
  psum_s[r][c2] = psum;
  __syncthreads();
  if (t < 16) {
    float tot = 0.f;
#pragma unroll
    for (int i = 0; i < 16; i++) tot += psum_s[t][i];
    inv_s[t] = (tot > 0.f) ? 1.f / tot : 0.f;
  }
  __syncthreads();
#pragma unroll
  for (int reg = 0; reg < 4; reg++) {
    int row = quad * 4 + reg;
    float out = acc[reg] * inv_s[row];
    hout[((size_t)(h * N_NODES + row_base + n0l + row) << 6) + wv * 16 + m0] = out;
  }
}

// K4: nodes_out = l2norm(nodes + h @ Wo^T + bo)
template <bool BF16>
__global__ __launch_bounds__(128) void k_out(
    const int* __restrict__ flag,
    const void* __restrict__ nodes, const void* __restrict__ Wo,
    const void* __restrict__ bo, const float* __restrict__ hout,
    void* __restrict__ out_base) {
  if ((*flag != 0) != BF16) return;
  int n = blockIdx.x, t = threadIdx.x;
  __shared__ float hv[QK_DIM * N_HEADS];
  __shared__ float red[128];
  for (int i = t; i < QK_DIM * N_HEADS; i += 128) {
    int d = i >> 3, hh = i & 7;
    hv[i] = hout[((size_t)(hh * N_NODES + n) << 6) + d];
  }
  __syncthreads();
  float val = ldv<BF16>(nodes, (size_t)n * D_NODE + t) + ldv<BF16>(bo, t);
  for (int ch = 0; ch < (QK_DIM * N_HEADS) / 8; ch++) {
    float wf[8];
    ld8v<BF16>(Wo, (size_t)t * ((QK_DIM * N_HEADS) / 8) + ch, wf);
#pragma unroll
    for (int j = 0; j < 8; j++) val += wf[j] * hv[ch * 8 + j];
  }
  red[t] = val * val;
  __syncthreads();
  for (int s = 64; s > 0; s >>= 1) {
    if (t < s) red[t] += red[t + s];
    __syncthreads();
  }
  float ss = red[0];
  stv<BF16>(out_base, (size_t)n * D_NODE + t, val / (sqrtf(ss) + 1e-8f));
}

extern "C" void kernel_launch(void* const* d_in, const int* in_sizes, int n_in,
                              void* d_out, int out_size, void* d_ws, size_t ws_size,
                              hipStream_t stream) {
  const void* nodes = d_in[0];
  const void* adj   = d_in[1];
  const void* edges = d_in[2];
  const void* WQ = d_in[3];
  const void* WK = d_in[4];
  const void* WV = d_in[5];
  const void* Wo = d_in[6];
  const void* bo = d_in[7];
  const void* We = d_in[8];
  const void* Weo = d_in[9];

  // ws layout: [flag 256B][rowmax 64KB][qhi qlo khi klo vT : 5 x 2MB][hout 4MB][smod]
  char* w = (char*)d_ws;
  int* flag = (int*)w;
  unsigned* rowmax = (unsigned*)(w + 256);
  size_t off = 256 + (size_t)N_NODES * N_HEADS * 4;
  const size_t PLANE = (size_t)N_HEADS * N_NODES * QK_DIM * 2;  // 2 MB
  u16* qhi = (u16*)(w + off);            off += PLANE;
  u16* qlo = (u16*)(w + off);            off += PLANE;
  u16* khi = (u16*)(w + off);            off += PLANE;
  u16* klo = (u16*)(w + off);            off += PLANE;
  u16* vT  = (u16*)(w + off);            off += PLANE;
  float* hout = (float*)(w + off);       off += (size_t)N_NODES * QK_DIM * N_HEADS * 4;
  u16* smod_g = (u16*)(w + off);
  const size_t SMOD_FULL = (size_t)N_HEADS * N_NODES * N_NODES * 2;  // 67 MB

  int nsl = 128;
  for (int s = 1; s <= 128; s *= 2) {
    if (off + SMOD_FULL / s <= ws_size) { nsl = s; break; }
  }
  int rows_per = N_NODES / nsl;

  hipMemsetAsync(rowmax, 0, (size_t)N_NODES * N_HEADS * sizeof(unsigned), stream);
  k_detect<<<1, 64, 0, stream>>>((const unsigned*)adj, flag);

  dim3 g1(N_NODES / 16, 24);
  k_proj<false><<<g1, 256, 0, stream>>>(flag, nodes, WQ, WK, WV, qhi, qlo, khi, klo, vT);
  k_proj<true ><<<g1, 256, 0, stream>>>(flag, nodes, WQ, WK, WV, qhi, qlo, khi, klo, vT);

  for (int s = 0; s < nsl; s++) {
    int row_base = s * rows_per;
    dim3 g2(N_NODES / 16, rows_per / 16);
    k_scores<false><<<g2, 256, 0, stream>>>(flag, row_base, rows_per, adj, edges, We, Weo,
                                            qhi, qlo, khi, klo, rowmax, smod_g, d_out);
    k_scores<true ><<<g2, 256, 0, stream>>>(flag, row_base, rows_per, adj, edges, We, Weo,
                                            qhi, qlo, khi, klo, rowmax, smod_g, d_out);
    dim3 g3(N_HEADS, rows_per / 16);
    k_attn<false><<<g3, 256, 0, stream>>>(flag, row_base, rows_per, smod_g, vT, rowmax, hout);
    k_attn<true ><<<g3, 256, 0, stream>>>(flag, row_base, rows_per, smod_g, vT, rowmax, hout);
  }

  k_out<false><<<N_NODES, 128, 0, stream>>>(flag, nodes, Wo, bo, hout, d_out);
  k_out<true ><<<N_NODES, 128, 0, stream>>>(flag, nodes, Wo, bo, hout, d_out);
}

// Round 5
// 496.379 us; speedup vs baseline: 3.7169x; 1.0983x over previous
//
#include <hip/hip_runtime.h>
#include <hip/hip_bf16.h>

#define N_NODES 2048
#define D_NODE 128
#define QK_DIM 64
#define N_HEADS 8
#define E_DIM 8
#define EXP_SHIFT 24.0f

typedef __hip_bfloat16 bf16;
typedef unsigned short u16;
typedef __attribute__((ext_vector_type(8))) short bf16x8v;
typedef __attribute__((ext_vector_type(4))) float f32x4v;

__device__ __forceinline__ float bf2f(bf16 x) { return __bfloat162float(x); }
__device__ __forceinline__ float u2f(u16 u) { return __uint_as_float(((unsigned)u) << 16); }
__device__ __forceinline__ u16 f2bf(float f) {
  unsigned u = __float_as_uint(f);
  unsigned r = u + 0x7FFFu + ((u >> 16) & 1u);
  return (u16)(r >> 16);
}

__device__ __forceinline__ void unpack2(unsigned u, float& a, float& b) {
  union { unsigned x; float f; } lo, hi;
  lo.x = u << 16; hi.x = u & 0xffff0000u;
  a = lo.f; b = hi.f;
}
__device__ __forceinline__ void unpack8(uint4 u, float* f) {
  unpack2(u.x, f[0], f[1]); unpack2(u.y, f[2], f[3]);
  unpack2(u.z, f[4], f[5]); unpack2(u.w, f[6], f[7]);
}

template <bool BF16>
__device__ __forceinline__ float ldv(const void* p, size_t i) {
  if constexpr (BF16) return bf2f(((const bf16*)p)[i]);
  else return ((const float*)p)[i];
}
template <bool BF16>
__device__ __forceinline__ void ld8v(const void* p, size_t i8, float* f) {
  if constexpr (BF16) {
    uint4 u = ((const uint4*)p)[i8];
    unpack8(u, f);
  } else {
    const float4* fp = (const float4*)p;
    float4 a = fp[2 * i8], b = fp[2 * i8 + 1];
    f[0] = a.x; f[1] = a.y; f[2] = a.z; f[3] = a.w;
    f[4] = b.x; f[5] = b.y; f[6] = b.z; f[7] = b.w;
  }
}
template <bool BF16>
__device__ __forceinline__ void stv(void* p, size_t i, float v) {
  if constexpr (BF16) ((bf16*)p)[i] = __float2bfloat16(v);
  else ((float*)p)[i] = v;
}
template <bool BF16>
__device__ __forceinline__ void st8v(void* p, size_t i8, const float* f) {
  if constexpr (BF16) {
    union { uint4 u; u16 b[8]; } ou;
#pragma unroll
    for (int e = 0; e < 8; e++) ou.b[e] = f2bf(f[e]);
    ((uint4*)p)[i8] = ou.u;
  } else {
    ((float4*)p)[2 * i8] = make_float4(f[0], f[1], f[2], f[3]);
    ((float4*)p)[2 * i8 + 1] = make_float4(f[4], f[5], f[6], f[7]);
  }
}

// MFMA fragment load: 8 consecutive bf16 elements at elem (16B-aligned).
template <bool BF16>
__device__ __forceinline__ bf16x8v ld_frag(const void* p, size_t elem) {
  if constexpr (BF16) {
    return *(const bf16x8v*)((const u16*)p + elem);
  } else {
    const float4* fp = (const float4*)p;
    float4 a = fp[elem / 4], b = fp[elem / 4 + 1];
    union { bf16x8v v; u16 s[8]; } o;
    o.s[0] = f2bf(a.x); o.s[1] = f2bf(a.y); o.s[2] = f2bf(a.z); o.s[3] = f2bf(a.w);
    o.s[4] = f2bf(b.x); o.s[5] = f2bf(b.y); o.s[6] = f2bf(b.z); o.s[7] = f2bf(b.w);
    return o.v;
  }
}

// K0: dtype detect via adj[0][0]==1.0 (self-loop). bf16 word0 low16==0x3F80.
__global__ void k_detect(const unsigned* __restrict__ adj_words, int* __restrict__ flag) {
  if (threadIdx.x == 0 && blockIdx.x == 0) {
    int b = 0;
    for (int i = 0; i < 64; i++)
      if ((adj_words[i] & 0xFFFFu) == 0x3F80u) b = 1;
    *flag = b;
  }
}

// K1: projections as MFMA GEMM. Block = 16 nodes x 64 features (4 waves x 16 feat).
// grid (N/16, 24): mat = y>>3 (0=Q,1=K,2=V). Q/K stored hi/lo split [h][n][64];
// V stored directly transposed as vT[h][d][n].
template <bool BF16>
__global__ __launch_bounds__(256) void k_proj(
    const int* __restrict__ flag,
    const void* __restrict__ nodes, const void* __restrict__ WQ,
    const void* __restrict__ WK, const void* __restrict__ WV,
    u16* __restrict__ qhi, u16* __restrict__ qlo,
    u16* __restrict__ khi, u16* __restrict__ klo, u16* __restrict__ vT) {
  if ((*flag != 0) != BF16) return;
  int t = threadIdx.x;
  int n0 = blockIdx.x * 16;
  int g = blockIdx.y;
  int mat = g >> 3;
  const void* W = (mat == 0) ? WQ : (mat == 1) ? WK : WV;
  int wv = t >> 6, lane = t & 63, m0 = lane & 15, quad = lane >> 4;
  int c = (g & 7) * 64 + wv * 16 + m0;
  f32x4v acc = {0.f, 0.f, 0.f, 0.f};
#pragma unroll
  for (int kk = 0; kk < 4; kk++) {
    bf16x8v af = ld_frag<BF16>(nodes, (size_t)(n0 + m0) * D_NODE + kk * 32 + quad * 8);
    bf16x8v bfr = ld_frag<BF16>(W, (size_t)c * D_NODE + kk * 32 + quad * 8);
    acc = __builtin_amdgcn_mfma_f32_16x16x32_bf16(af, bfr, acc, 0, 0, 0);
  }
  int d = c >> 3, h = c & 7;
  if (mat == 2) {
    union { unsigned w[2]; u16 s[4]; } ob;
#pragma unroll
    for (int reg = 0; reg < 4; reg++) ob.s[reg] = f2bf(acc[reg]);
    int n = n0 + quad * 4;
    unsigned* dst = (unsigned*)(vT + ((size_t)(h * QK_DIM + d)) * N_NODES + n);
    dst[0] = ob.w[0]; dst[1] = ob.w[1];
  } else {
    u16* hiP = (mat == 0) ? qhi : khi;
    u16* loP = (mat == 0) ? qlo : klo;
    float scale = (mat == 0) ? 0.125f : 1.f;
#pragma unroll
    for (int reg = 0; reg < 4; reg++) {
      int n = n0 + quad * 4 + reg;
      float vq = acc[reg] * scale;
      u16 hi = f2bf(vq);
      u16 lo = f2bf(vq - u2f(hi));
      size_t o = ((size_t)(h * N_NODES + n) << 6) + d;
      hiP[o] = hi; loP[o] = lo;
    }
  }
}

// K2 (fused): per (col-split, 16-row strip): iterate 256/S-col tiles:
//   S=QK^T (MFMA, hi/lo), smod=S*we*adj (fp32), edges_out, p=exp(smod-C),
//   PV accumulate via MFMA. Writes hout_p[n][split][h][d], psum_p[n][split*8+h].
// No row max needed: exp(s-C)/sum == exp(s-m)/sum for any constant C.
template <bool BF16>
__global__ __launch_bounds__(256, 3) void k_fused(
    const int* __restrict__ flag, int S,
    const void* __restrict__ adj, const void* __restrict__ edges,
    const void* __restrict__ We, const void* __restrict__ Weo,
    const u16* __restrict__ qhi, const u16* __restrict__ qlo,
    const u16* __restrict__ khi, const u16* __restrict__ klo,
    const u16* __restrict__ vT,
    float* __restrict__ hout_p, float* __restrict__ psum_p,
    void* __restrict__ out_base) {
  if ((*flag != 0) != BF16) return;
  __shared__ float We_s[N_HEADS][E_DIM];
  __shared__ float Weo_s[E_DIM][N_HEADS];
  __shared__ float we_s[N_HEADS][256];
  __shared__ float smod_s[N_HEADS][256];
  __shared__ u16 p_tile[N_HEADS][16][32];
  int t = threadIdx.x;
  if (t < 64) { We_s[t >> 3][t & 7] = ldv<BF16>(We, t); Weo_s[t >> 3][t & 7] = ldv<BF16>(Weo, t); }
  int split = blockIdx.x, rt = blockIdx.y;
  int row0 = rt * 16;
  int ntiles = (N_NODES / 16) / S;
  int colbase = split * ntiles * 16;
  int r = t >> 4, cc = t & 15;
  int wv = t >> 6, lane = t & 63, m0 = lane & 15, quad = lane >> 4;
  float psum[N_HEADS];
#pragma unroll
  for (int h = 0; h < 8; h++) psum[h] = 0.f;
  f32x4v acc_pv[2][4];
#pragma unroll
  for (int hh = 0; hh < 2; hh++)
#pragma unroll
    for (int dc = 0; dc < 4; dc++) acc_pv[hh][dc] = (f32x4v){0.f, 0.f, 0.f, 0.f};

  void* edges_out = (char*)out_base + (size_t)N_NODES * D_NODE * (BF16 ? 2 : 4);

  for (int ct = 0; ct < ntiles; ct++) {
    int col0 = colbase + ct * 16;
    // --- phase 1 (pair-parallel): load adj/edges, compute we*a ---
    int n = row0 + r, col = col0 + cc;
    size_t pair = (size_t)n * N_NODES + col;
    float a = ldv<BF16>(adj, pair);
    float e8[8];
    ld8v<BF16>(edges, pair, e8);
    __syncthreads();  // previous tile's smod_s/p_tile consumers done; we_s free
#pragma unroll
    for (int h = 0; h < 8; h++) {
      float we = 0.f;
#pragma unroll
      for (int e = 0; e < 8; e++) we += e8[e] * We_s[h][e];
      we_s[h][t] = we * a;
    }
    __syncthreads();  // we_s visible
    // --- phase 2 (wave-parallel): QK^T MFMA, smod -> LDS ---
#pragma unroll
    for (int hh = 0; hh < 2; hh++) {
      int h = wv * 2 + hh;
      f32x4v acc = {0.f, 0.f, 0.f, 0.f};
#pragma unroll
      for (int kh = 0; kh < 2; kh++) {
        size_t qoff = ((size_t)(h * N_NODES + row0 + m0) << 6) + kh * 32 + quad * 8;
        size_t koff = ((size_t)(h * N_NODES + col0 + m0) << 6) + kh * 32 + quad * 8;
        bf16x8v ah = *(const bf16x8v*)(qhi + qoff);
        bf16x8v al = *(const bf16x8v*)(qlo + qoff);
        bf16x8v bh = *(const bf16x8v*)(khi + koff);
        bf16x8v bl = *(const bf16x8v*)(klo + koff);
        acc = __builtin_amdgcn_mfma_f32_16x16x32_bf16(ah, bh, acc, 0, 0, 0);
        acc = __builtin_amdgcn_mfma_f32_16x16x32_bf16(ah, bl, acc, 0, 0, 0);
        acc = __builtin_amdgcn_mfma_f32_16x16x32_bf16(al, bh, acc, 0, 0, 0);
      }
#pragma unroll
      for (int reg = 0; reg < 4; reg++) {
        int pidx = (quad * 4 + reg) * 16 + m0;
        smod_s[h][pidx] = acc[reg] * we_s[h][pidx];
      }
    }
    __syncthreads();  // smod_s visible
    // --- phase 3 (pair-parallel): edges_out, p = exp(smod - C) ---
    {
      float sm[8];
#pragma unroll
      for (int h = 0; h < 8; h++) sm[h] = smod_s[h][t];
      float ss = 0.f, eo[8];
#pragma unroll
      for (int e = 0; e < 8; e++) {
        float x = e8[e];
#pragma unroll
        for (int h = 0; h < 8; h++) x += sm[h] * Weo_s[e][h];
        eo[e] = x; ss += x * x;
      }
      float inv = 1.f / (sqrtf(ss) + 1e-8f);
#pragma unroll
      for (int e = 0; e < 8; e++) eo[e] *= inv;
      st8v<BF16>(edges_out, pair, eo);
      int half = (ct & 1) * 16;
#pragma unroll
      for (int h = 0; h < 8; h++) {
        float p = (a != 0.f) ? __expf(sm[h] - EXP_SHIFT) : 0.f;
        psum[h] += p;
        p_tile[h][r][half + cc] = f2bf(p);
      }
    }
    // --- phase 4: PV MFMA every 2 tiles (K=32) ---
    if (ct & 1) {
      __syncthreads();  // p_tile both halves visible
      int colk = colbase + (ct - 1) * 16;
#pragma unroll
      for (int hh = 0; hh < 2; hh++) {
        int h = wv * 2 + hh;
        bf16x8v ap = *(const bf16x8v*)(&p_tile[h][0][0] + m0 * 32 + quad * 8);
#pragma unroll
        for (int dc = 0; dc < 4; dc++) {
          bf16x8v bp = *(const bf16x8v*)(vT + ((size_t)(h * QK_DIM + dc * 16 + m0)) * N_NODES + colk + quad * 8);
          acc_pv[hh][dc] = __builtin_amdgcn_mfma_f32_16x16x32_bf16(ap, bp, acc_pv[hh][dc], 0, 0, 0);
        }
      }
    }
  }
  // --- epilogue: psum reduce over the 16 col-lanes; write partials ---
#pragma unroll
  for (int h = 0; h < 8; h++) {
    float x = psum[h];
    x += __shfl_xor(x, 1); x += __shfl_xor(x, 2);
    x += __shfl_xor(x, 4); x += __shfl_xor(x, 8);
    if ((t & 15) == 0)
      psum_p[((size_t)(row0 + r)) * (S * 8) + split * 8 + h] = x;
  }
#pragma unroll
  for (int hh = 0; hh < 2; hh++) {
    int h = wv * 2 + hh;
#pragma unroll
    for (int dc = 0; dc < 4; dc++) {
#pragma unroll
      for (int reg = 0; reg < 4; reg++) {
        int n = row0 + quad * 4 + reg;
        hout_p[((size_t)n * S + split) * 512 + h * 64 + dc * 16 + m0] = acc_pv[hh][dc][reg];
      }
    }
  }
}

// K4: merge partials + nodes_out = l2norm(nodes + h @ Wo^T + bo)
template <bool BF16>
__global__ __launch_bounds__(128) void k_out(
    const int* __restrict__ flag, int S,
    const void* __restrict__ nodes, const void* __restrict__ Wo,
    const void* __restrict__ bo,
    const float* __restrict__ hout_p, const float* __restrict__ psum_p,
    void* __restrict__ out_base) {
  if ((*flag != 0) != BF16) return;
  int n = blockIdx.x, t = threadIdx.x;
  __shared__ float hv[QK_DIM * N_HEADS];
  __shared__ float inv_s[N_HEADS];
  __shared__ float red[128];
  if (t < 8) {
    float tot = 0.f;
    for (int s = 0; s < S; s++) tot += psum_p[(size_t)n * (S * 8) + s * 8 + t];
    inv_s[t] = (tot > 0.f) ? 1.f / tot : 0.f;
  }
  __syncthreads();
  for (int i = t; i < QK_DIM * N_HEADS; i += 128) {
    int d = i >> 3, hh = i & 7;
    float acc = 0.f;
    for (int s = 0; s < S; s++)
      acc += hout_p[((size_t)n * S + s) * 512 + hh * 64 + d];
    hv[i] = acc * inv_s[hh];
  }
  __syncthreads();
  float val = ldv<BF16>(nodes, (size_t)n * D_NODE + t) + ldv<BF16>(bo, t);
  for (int ch = 0; ch < (QK_DIM * N_HEADS) / 8; ch++) {
    float wf[8];
    ld8v<BF16>(Wo, (size_t)t * ((QK_DIM * N_HEADS) / 8) + ch, wf);
#pragma unroll
    for (int j = 0; j < 8; j++) val += wf[j] * hv[ch * 8 + j];
  }
  red[t] = val * val;
  __syncthreads();
  for (int s = 64; s > 0; s >>= 1) {
    if (t < s) red[t] += red[t + s];
    __syncthreads();
  }
  float ss = red[0];
  stv<BF16>(out_base, (size_t)n * D_NODE + t, val / (sqrtf(ss) + 1e-8f));
}

extern "C" void kernel_launch(void* const* d_in, const int* in_sizes, int n_in,
                              void* d_out, int out_size, void* d_ws, size_t ws_size,
                              hipStream_t stream) {
  const void* nodes = d_in[0];
  const void* adj   = d_in[1];
  const void* edges = d_in[2];
  const void* WQ = d_in[3];
  const void* WK = d_in[4];
  const void* WV = d_in[5];
  const void* Wo = d_in[6];
  const void* bo = d_in[7];
  const void* We = d_in[8];
  const void* Weo = d_in[9];

  // ws: [flag 256B][qhi qlo khi klo vT : 5 x 2MB][hout_p S*4MB][psum_p S*64KB]
  char* w = (char*)d_ws;
  int* flag = (int*)w;
  size_t off = 256;
  const size_t PLANE = (size_t)N_HEADS * N_NODES * QK_DIM * 2;  // 2 MB
  u16* qhi = (u16*)(w + off);  off += PLANE;
  u16* qlo = (u16*)(w + off);  off += PLANE;
  u16* khi = (u16*)(w + off);  off += PLANE;
  u16* klo = (u16*)(w + off);  off += PLANE;
  u16* vT  = (u16*)(w + off);  off += PLANE;

  int S = 8;
  while (S > 1 && off + (size_t)S * ((size_t)N_NODES * 512 * 4 + N_NODES * 8 * 4) > ws_size)
    S >>= 1;
  float* hout_p = (float*)(w + off);
  off += (size_t)S * N_NODES * 512 * 4;
  float* psum_p = (float*)(w + off);

  k_detect<<<1, 64, 0, stream>>>((const unsigned*)adj, flag);

  dim3 g1(N_NODES / 16, 24);
  k_proj<false><<<g1, 256, 0, stream>>>(flag, nodes, WQ, WK, WV, qhi, qlo, khi, klo, vT);
  k_proj<true ><<<g1, 256, 0, stream>>>(flag, nodes, WQ, WK, WV, qhi, qlo, khi, klo, vT);

  dim3 g2(S, N_NODES / 16);
  k_fused<false><<<g2, 256, 0, stream>>>(flag, S, adj, edges, We, Weo,
                                         qhi, qlo, khi, klo, vT, hout_p, psum_p, d_out);
  k_fused<true ><<<g2, 256, 0, stream>>>(flag, S, adj, edges, We, Weo,
                                         qhi, qlo, khi, klo, vT, hout_p, psum_p, d_out);

  k_out<false><<<N_NODES, 128, 0, stream>>>(flag, S, nodes, Wo, bo, hout_p, psum_p, d_out);
  k_out<true ><<<N_NODES, 128, 0, stream>>>(flag, S, nodes, Wo, bo, hout_p, psum_p, d_out);
}